// Round 18
// baseline (108.750 us; speedup 1.0000x reference)
//
#include <hip/hip_runtime.h>
#include <cmath>

// Problem constants
constexpr int B_ = 4, C_ = 512, H_ = 56, W_ = 56;
constexpr int HW_ = H_ * W_;          // 3136
constexpr int NPIX = B_ * HW_;        // 12544
constexpr int G_ = 16, P_ = 9;
constexpr int NMSK = G_ * P_;         // 144
constexpr int GEMM_BLOCKS = 1568;     // (12544/64) * (512/64)
constexpr int GEMM2_BLOCKS = 1372;    // (12544/64) * 7 col-tiles (cols 0..447)
constexpr int TRANS_BLOCKS = (HW_ / 32) * (C_ / 32) * B_;   // 6272
constexpr int PREP_BLOCKS = 16 * 16 * 3;                     // 768

typedef __attribute__((ext_vector_type(8))) short short8;
typedef __attribute__((ext_vector_type(4))) float f32x4;

__device__ __forceinline__ float b2f(ushort u) {
    union { unsigned int i; float f; } v; v.i = (unsigned int)u << 16; return v.f;
}
__device__ __forceinline__ ushort f2b(float f) {
    unsigned int x = __float_as_uint(f);
    unsigned int r = (x + 0x7fffu + ((x >> 16) & 1u)) >> 16;
    return (ushort)r;
}
__device__ __forceinline__ void gload16(const ushort* g, ushort* l) {
    __builtin_amdgcn_global_load_lds(
        (const __attribute__((address_space(1))) unsigned int*)g,
        (__attribute__((address_space(3))) unsigned int*)l, 16, 0, 0);
}

// LDS union: 64x64 A/B staging (16 KB) aliases MODE2 transpose buf (17.2 KB).
union GemmSMem {
    struct { ushort As[64 * 64]; ushort Bs[64 * 64]; } s;
    float eb[64 * 67];
};

// ---------------------------------------------------------------------------
// K0 (fused): role-branched pre-stage.
//   blocks [0, 6272):   NCHW->NHWC transpose, fp32 -> bf16
//   blocks [6272, 7040): weight prep ([K][N] -> bf16 [N][K]; z=2 fuses
//                        off|mask concat: cols 0..287=w_off, 288..431=w_mask,
//                        432..511=zero; + fused bias vector)
// ---------------------------------------------------------------------------
__global__ __launch_bounds__(256) void pre_kernel(
    const float* __restrict__ x, ushort* __restrict__ xh,
    const float* __restrict__ w_in, const float* __restrict__ w_off,
    const float* __restrict__ w_mask, const float* __restrict__ w_out,
    const float* __restrict__ b_off, const float* __restrict__ b_mask,
    ushort* __restrict__ wtA, ushort* __restrict__ wtOM, ushort* __restrict__ wtO,
    float* __restrict__ bOM)
{
    __shared__ float tile[32][33];
    int bid = blockIdx.x;
    int tx = threadIdx.x, ty = threadIdx.y;
    if (bid < TRANS_BLOCKS) {
        int bx = bid % 98;
        int rem = bid / 98;
        int by = rem % 16;
        int bz = rem / 16;
        int hw0 = bx * 32, c0 = by * 32;
        const float* ib = x + (size_t)bz * C_ * HW_;
        #pragma unroll
        for (int i = ty; i < 32; i += 8)
            tile[i][tx] = ib[(size_t)(c0 + i) * HW_ + hw0 + tx];
        __syncthreads();
        ushort* ob = xh + (size_t)bz * HW_ * C_;
        #pragma unroll
        for (int i = ty; i < 32; i += 8)
            ob[(size_t)(hw0 + i) * C_ + c0 + tx] = f2b(tile[tx][i]);
    } else {
        int p = bid - TRANS_BLOCKS;
        int px = p % 16;
        int py = (p / 16) % 16;
        int pz = p / 256;
        int k0 = px * 32;   // K (input row)
        int n0 = py * 32;   // N (input col / output row)
        for (int i = ty; i < 32; i += 8) {
            int k = k0 + i, n = n0 + tx;
            float v;
            if (pz == 0) v = w_in[k * 512 + n];
            else if (pz == 1) v = w_out[k * 512 + n];
            else v = (n < 288) ? w_off[k * 288 + n]
                               : (n < 432 ? w_mask[k * 144 + (n - 288)] : 0.f);
            tile[i][tx] = v;
        }
        __syncthreads();
        ushort* dst = (pz == 0) ? wtA : (pz == 1 ? wtO : wtOM);
        for (int i = ty; i < 32; i += 8)
            dst[(size_t)(n0 + i) * 512 + k0 + tx] = f2b(tile[tx][i]);
        if (pz == 2 && px == 0 && py == 0) {
            int t = ty * 32 + tx;
            for (int tt = t; tt < 512; tt += 256)
                bOM[tt] = (tt < 288) ? b_off[tt] : (tt < 432 ? b_mask[tt - 288] : 0.f);
        }
    }
}

// ---------------------------------------------------------------------------
// GEMM body.  C[M=12544 x 512] = A[M x 512]bf16 * Bt^T + bias.
// BM=BN=64, BK=64, 4 waves 2x2 (32x32/wave). Single-buffered (dbuf = 5.4M
// conflicts, R8). Chunk-XOR LDS layout.
// MODE: 0 = fp32 out; 1 = bf16 out; 2 = BN+SiLU -> NCHW fp32 via block-wide
// [64][67] LDS transpose (256 B coalesced channel-plane stores).
// ---------------------------------------------------------------------------
template <int MODE>
__device__ __forceinline__ void gemm_body(
    ushort* __restrict__ As, ushort* __restrict__ Bs, float* __restrict__ ebf,
    int row0, int col0, const ushort* __restrict__ A, const ushort* __restrict__ Bt,
    const float* __restrict__ bias, void* __restrict__ Cout,
    const float* __restrict__ bng, const float* __restrict__ bnb,
    const float* __restrict__ bnm, const float* __restrict__ bnv)
{
    int tid = threadIdx.x;
    int lane = tid & 63, wid = tid >> 6;
    int wm = wid >> 1, wn = wid & 1;

    f32x4 acc[2][2] = {};

    int lr = lane >> 3;               // sub-row within 8-row stripe
    int sc = (lane & 7) ^ lr;         // swizzled source chunk (0..7)

    for (int k0 = 0; k0 < 512; k0 += 64) {
        if (k0) __syncthreads();
        #pragma unroll
        for (int i = 0; i < 2; i++) {
            int s = wid * 2 + i;              // 8-row stripe index (0..7)
            gload16(A + (size_t)(row0 + s * 8 + lr) * 512 + k0 + sc * 8, &As[s * 512]);
            gload16(Bt + (size_t)(col0 + s * 8 + lr) * 512 + k0 + sc * 8, &Bs[s * 512]);
        }
        __syncthreads();
        #pragma unroll
        for (int ks = 0; ks < 2; ks++) {
            short8 af[2], bf[2];
            #pragma unroll
            for (int mi = 0; mi < 2; mi++) {
                int r = wm * 32 + mi * 16 + (lane & 15);
                int c = ((lane >> 4) + ks * 4) ^ (r & 7);
                af[mi] = *(const short8*)((const char*)As + r * 128 + c * 16);
            }
            #pragma unroll
            for (int ni = 0; ni < 2; ni++) {
                int r = wn * 32 + ni * 16 + (lane & 15);
                int c = ((lane >> 4) + ks * 4) ^ (r & 7);
                bf[ni] = *(const short8*)((const char*)Bs + r * 128 + c * 16);
            }
            #pragma unroll
            for (int mi = 0; mi < 2; mi++)
                #pragma unroll
                for (int ni = 0; ni < 2; ni++)
                    acc[mi][ni] = __builtin_amdgcn_mfma_f32_16x16x32_bf16(
                        af[mi], bf[ni], acc[mi][ni], 0, 0, 0);
        }
    }

    if constexpr (MODE == 2) {
        __syncthreads();   // ebf aliases As/Bs: wait for all waves' MFMAs
        #pragma unroll
        for (int ni = 0; ni < 2; ni++) {
            int cl = wn * 32 + ni * 16 + (lane & 15);    // local chan 0..63
            int col = col0 + cl;
            float bv = bias[col];
            float inv = rsqrtf(bnv[col] + 1e-5f);
            float bsc = bng[col] * inv;
            float bsh = bnb[col] - bnm[col] * bsc;
            int rl = (lane >> 4) * 4;
            #pragma unroll
            for (int mi = 0; mi < 2; mi++)
                #pragma unroll
                for (int r = 0; r < 4; r++) {
                    float val = acc[mi][ni][r] + bv;
                    float t2 = val * bsc + bsh;
                    float s = t2 / (1.f + expf(-t2));
                    ebf[cl * 67 + wm * 32 + mi * 16 + rl + r] = s;
                }
        }
        __syncthreads();
        int bb = row0 / HW_;
        int hw0 = row0 - bb * HW_;    // 64-blocks never cross batch (3136%64==0)
        float* ob = (float*)Cout + (size_t)bb * C_ * HW_ + hw0 + lane;
        #pragma unroll
        for (int it = 0; it < 16; it++) {
            int chan = it * 4 + wid;
            ob[(size_t)(col0 + chan) * HW_] = ebf[chan * 67 + lane];
        }
    } else {
        #pragma unroll
        for (int ni = 0; ni < 2; ni++) {
            int col = col0 + wn * 32 + ni * 16 + (lane & 15);
            float bv = bias[col];
            #pragma unroll
            for (int mi = 0; mi < 2; mi++) {
                int rowb = row0 + wm * 32 + mi * 16 + (lane >> 4) * 4;
                #pragma unroll
                for (int r = 0; r < 4; r++) {
                    float val = acc[mi][ni][r] + bv;
                    if constexpr (MODE == 0)
                        ((float*)Cout)[(size_t)(rowb + r) * 512 + col] = val;
                    else
                        ((ushort*)Cout)[(size_t)(rowb + r) * 512 + col] = f2b(val);
                }
            }
        }
    }
}

template <int MODE>
__global__ __launch_bounds__(256) void mfma_gemm_kernel(
    const ushort* __restrict__ A, const ushort* __restrict__ Bt,
    const float* __restrict__ bias, void* __restrict__ Cout,
    const float* __restrict__ bng, const float* __restrict__ bnb,
    const float* __restrict__ bnm, const float* __restrict__ bnv)
{
    __shared__ GemmSMem sm;
    int bid = blockIdx.x;
    int wgid = (bid & 7) * (GEMM_BLOCKS / 8) + (bid >> 3);   // XCD chunks
    gemm_body<MODE>(sm.s.As, sm.s.Bs, sm.eb, (wgid >> 3) * 64, (wgid & 7) * 64,
                    A, Bt, bias, Cout, bng, bnb, bnm, bnv);
}

// GEMM2: compacted 1372-block grid over 7 col-tiles (cols 448..511 are
// zero-weight and unread). Bijective XCD swizzle for nwg%8!=0 (m204 form):
// q=171, r=4 -> xcd<4 gets 172 chunks, else 171.
__global__ __launch_bounds__(256) void gemm2_kernel(
    const ushort* __restrict__ A, const ushort* __restrict__ Bt,
    const float* __restrict__ bias, void* __restrict__ Cout)
{
    __shared__ GemmSMem sm;
    int bid = blockIdx.x;
    int xcd = bid & 7;
    int wl = (xcd < 4 ? xcd * 172 : 688 + (xcd - 4) * 171) + (bid >> 3);
    int ct = wl % 7, mt = wl / 7;
    gemm_body<1>(sm.s.As, sm.s.Bs, sm.eb, mt * 64, ct * 64,
                 A, Bt, bias, Cout, nullptr, nullptr, nullptr, nullptr);
}

// ---------------------------------------------------------------------------
// dwln body: depthwise 3x3 conv (bf16) + LayerNorm(C) + exact GELU -> bf16.
// One WAVE per pixel; XCD-swizzled block order.
// ---------------------------------------------------------------------------
__device__ __forceinline__ void dwln_body(
    int bid, const ushort* __restrict__ xh, const float* __restrict__ wdw,
    const float* __restrict__ bdw, const float* __restrict__ lng,
    const float* __restrict__ lnb, ushort* __restrict__ x1)
{
    int tid = threadIdx.x;
    int wid = tid >> 6, lane = tid & 63;
    int j = (bid & 7) * (NPIX / 32) + (bid >> 3);   // 3136 blocks, %8==0
    int n = j * 4 + wid;
    int b = n / HW_, hw = n % HW_;
    int h = hw / W_, w = hw % W_;
    int c0 = lane * 8;
    const ushort* base = xh + (size_t)b * HW_ * C_ + c0;

    uint4 nb[9];
    #pragma unroll
    for (int ky = 0; ky < 3; ky++)
        #pragma unroll
        for (int kx = 0; kx < 3; kx++) {
            int hh = h + ky - 1, ww = w + kx - 1;
            bool ok = (hh >= 0) & (hh < H_) & (ww >= 0) & (ww < W_);
            nb[ky * 3 + kx] = ok ? *(const uint4*)(base + ((size_t)hh * W_ + ww) * C_)
                                 : make_uint4(0u, 0u, 0u, 0u);
        }

    float acc[8];
    {
        float4 b0 = *(const float4*)&bdw[c0];
        float4 b1 = *(const float4*)&bdw[c0 + 4];
        acc[0] = b0.x; acc[1] = b0.y; acc[2] = b0.z; acc[3] = b0.w;
        acc[4] = b1.x; acc[5] = b1.y; acc[6] = b1.z; acc[7] = b1.w;
    }
    #pragma unroll
    for (int p = 0; p < 9; p++) {
        float4 w0 = *(const float4*)&wdw[p * C_ + c0];
        float4 w1 = *(const float4*)&wdw[p * C_ + c0 + 4];
        float wv[8] = {w0.x, w0.y, w0.z, w0.w, w1.x, w1.y, w1.z, w1.w};
        unsigned int u[4] = {nb[p].x, nb[p].y, nb[p].z, nb[p].w};
        #pragma unroll
        for (int q = 0; q < 4; q++) {
            float lo = __uint_as_float(u[q] << 16);
            float hi = __uint_as_float(u[q] & 0xffff0000u);
            acc[2 * q]     += wv[2 * q]     * lo;
            acc[2 * q + 1] += wv[2 * q + 1] * hi;
        }
    }

    float s1 = 0.f, s2 = 0.f;
    #pragma unroll
    for (int q = 0; q < 8; q++) { s1 += acc[q]; s2 += acc[q] * acc[q]; }
    #pragma unroll
    for (int o = 32; o > 0; o >>= 1) {
        s1 += __shfl_xor(s1, o);
        s2 += __shfl_xor(s2, o);
    }
    float mean = s1 * (1.f / 512.f);
    float var = s2 * (1.f / 512.f) - mean * mean;
    float inv = rsqrtf(var + 1e-6f);

    float4 g0 = *(const float4*)&lng[c0];
    float4 g1 = *(const float4*)&lng[c0 + 4];
    float4 e0 = *(const float4*)&lnb[c0];
    float4 e1 = *(const float4*)&lnb[c0 + 4];
    float gv[8] = {g0.x, g0.y, g0.z, g0.w, g1.x, g1.y, g1.z, g1.w};
    float ev[8] = {e0.x, e0.y, e0.z, e0.w, e1.x, e1.y, e1.z, e1.w};
    unsigned int outw[4];
    #pragma unroll
    for (int q = 0; q < 4; q++) {
        float t0 = (acc[2 * q]     - mean) * inv * gv[2 * q]     + ev[2 * q];
        float t1 = (acc[2 * q + 1] - mean) * inv * gv[2 * q + 1] + ev[2 * q + 1];
        float ge0 = 0.5f * t0 * (1.f + erff(t0 * 0.70710678118654752f));
        float ge1 = 0.5f * t1 * (1.f + erff(t1 * 0.70710678118654752f));
        outw[q] = (unsigned int)f2b(ge0) | ((unsigned int)f2b(ge1) << 16);
    }
    *(uint4*)&x1[(size_t)n * C_ + c0] = make_uint4(outw[0], outw[1], outw[2], outw[3]);
}

// ---------------------------------------------------------------------------
// Fused K2a: GEMM1 (MFMA-bound) CONCURRENT with dwln (latency-bound).
// ---------------------------------------------------------------------------
__global__ __launch_bounds__(256) void g1_dwln_kernel(
    const ushort* __restrict__ xh, const ushort* __restrict__ wtA,
    const float* __restrict__ b_in, ushort* __restrict__ xpb,
    const float* __restrict__ wdw, const float* __restrict__ bdw,
    const float* __restrict__ lng, const float* __restrict__ lnb,
    ushort* __restrict__ x1)
{
    __shared__ GemmSMem sm;
    int bid = blockIdx.x;
    if (bid < GEMM_BLOCKS) {
        int wgid = (bid & 7) * (GEMM_BLOCKS / 8) + (bid >> 3);
        gemm_body<1>(sm.s.As, sm.s.Bs, sm.eb, (wgid >> 3) * 64, (wgid & 7) * 64,
                     xh, wtA, b_in, xpb, nullptr, nullptr, nullptr, nullptr);
    } else {
        dwln_body(bid - GEMM_BLOCKS, xh, wdw, bdw, lng, lnb, x1);
    }
}

// ---------------------------------------------------------------------------
// K4: softmax + deformable sampling (R12/R14-proven form: 1 pixel/block, 2
// channels/thread, LDS tables, 36 uint gathers register-staged). om bf16:
// [0..287]=offsets, [288..431]=logits. XCD-swizzled pixel order.
// Empirical optimum: R11 (wider gathers) null, R13 (redundant reg-prep)
// -33us, R15 (persistent 8-px pipelined) -8us. Latency hiding comes from
// 12544 small co-resident blocks (TLP).
// ---------------------------------------------------------------------------
__global__ __launch_bounds__(256) void dcn_sample_kernel(
    const ushort* __restrict__ xp, const ushort* __restrict__ om,
    ushort* __restrict__ y1)
{
    __shared__ float slog[NMSK];
    __shared__ float sw4[NMSK][4];
    __shared__ int   sa4[NMSK][4];
    int bid = blockIdx.x;
    int n = (bid & 7) * (NPIX / 8) + (bid >> 3);   // XCD-contiguous pixel bands
    int b = n / HW_, hw = n % HW_;
    int h = hw / W_, w = hw % W_;
    int tid = threadIdx.x;
    const ushort* omp = om + (size_t)n * 512;

    if (tid < NMSK) slog[tid] = b2f(omp[288 + tid]);
    __syncthreads();
    if (tid < G_) {
        float mx = -1e30f;
        #pragma unroll
        for (int p = 0; p < P_; p++) mx = fmaxf(mx, slog[tid * P_ + p]);
        float e[P_], s = 0.f;
        #pragma unroll
        for (int p = 0; p < P_; p++) { e[p] = expf(slog[tid * P_ + p] - mx); s += e[p]; }
        float invs = 1.f / s;
        #pragma unroll
        for (int p = 0; p < P_; p++) slog[tid * P_ + p] = e[p] * invs;
    }
    __syncthreads();
    if (tid < NMSK) {
        int g = tid / 9, p = tid - g * 9;
        float ox = b2f(omp[g * 18 + p * 2 + 0]);
        float oy = b2f(omp[g * 18 + p * 2 + 1]);
        float px = (float)(w + (p / 3)) + ox;   // padded coords
        float py = (float)(h + (p % 3)) + oy;
        float x0f = floorf(px), y0f = floorf(py);
        float tx = px - x0f, ty = py - y0f;
        int x0 = (int)x0f, y0 = (int)y0f;
        float m = slog[tid];
        float ww[4] = { (1.f - ty) * (1.f - tx) * m, (1.f - ty) * tx * m,
                        ty * (1.f - tx) * m,         ty * tx * m };
        #pragma unroll
        for (int i = 0; i < 4; i++) {
            int yy = y0 + (i >> 1), xx = x0 + (i & 1);
            bool valid = (yy >= 1 && yy <= H_ && xx >= 1 && xx <= W_);
            sa4[tid][i] = valid ? ((yy - 1) * W_ + (xx - 1)) * C_ : 0;
            sw4[tid][i] = valid ? ww[i] : 0.f;
        }
    }
    __syncthreads();

    const ushort* xpb = xp + (size_t)b * HW_ * C_;
    int c0 = tid * 2;
    int g = tid >> 4;

    int addr[P_][4];
    #pragma unroll
    for (int p = 0; p < P_; p++)
        #pragma unroll
        for (int i = 0; i < 4; i++)
            addr[p][i] = sa4[g * 9 + p][i] + c0;

    unsigned int v[P_][4];
    #pragma unroll
    for (int p = 0; p < P_; p++)
        #pragma unroll
        for (int i = 0; i < 4; i++)
            v[p][i] = *(const unsigned int*)(xpb + addr[p][i]);

    float ax = 0.f, ay = 0.f;
    #pragma unroll
    for (int p = 0; p < P_; p++)
        #pragma unroll
        for (int i = 0; i < 4; i++) {
            float wgt = sw4[g * 9 + p][i];
            float lo = __uint_as_float(v[p][i] << 16);
            float hi = __uint_as_float(v[p][i] & 0xffff0000u);
            ax += wgt * lo;
            ay += wgt * hi;
        }

    ushort2 o; o.x = f2b(ax); o.y = f2b(ay);
    *(ushort2*)&y1[(size_t)n * 512 + c0] = o;
}

// ---------------------------------------------------------------------------
extern "C" void kernel_launch(void* const* d_in, const int* in_sizes, int n_in,
                              void* d_out, int out_size, void* d_ws, size_t ws_size,
                              hipStream_t stream)
{
    const float* x      = (const float*)d_in[0];
    const float* w_in   = (const float*)d_in[1];
    const float* b_in   = (const float*)d_in[2];
    const float* w_dw   = (const float*)d_in[3];
    const float* b_dw   = (const float*)d_in[4];
    const float* ln_g   = (const float*)d_in[5];
    const float* ln_b   = (const float*)d_in[6];
    const float* w_off  = (const float*)d_in[7];
    const float* b_off  = (const float*)d_in[8];
    const float* w_mask = (const float*)d_in[9];
    const float* b_mask = (const float*)d_in[10];
    const float* w_out  = (const float*)d_in[11];
    const float* b_out  = (const float*)d_in[12];
    const float* bn_g   = (const float*)d_in[13];
    const float* bn_b   = (const float*)d_in[14];
    const float* bn_m   = (const float*)d_in[15];
    const float* bn_v   = (const float*)d_in[16];
    float* out = (float*)d_out;

    const size_t NC = (size_t)NPIX * C_;         // 6,422,528
    char* wsp = (char*)d_ws;
    ushort* xh  = (ushort*)wsp;  wsp += NC * 2;              // bf16 [N][C]
    ushort* x1  = (ushort*)wsp;  wsp += NC * 2;              // bf16 [N][C]; y1 alias
    ushort* xpb = (ushort*)wsp;  wsp += NC * 2;              // bf16 [N][C] (sampler in)
    ushort* om  = (ushort*)wsp;  wsp += NC * 2;              // bf16 [N][512] off|mask
    ushort* wtA = (ushort*)wsp;  wsp += 512 * 512 * 2;
    ushort* wtOM= (ushort*)wsp;  wsp += 512 * 512 * 2;
    ushort* wtO = (ushort*)wsp;  wsp += 512 * 512 * 2;
    float*  bOM = (float*)wsp;   wsp += 512 * 4;

    dim3 tb(32, 8);
    // Fused transpose + weight prep (independent, role-branched).
    pre_kernel<<<TRANS_BLOCKS + PREP_BLOCKS, tb, 0, stream>>>(
        x, xh, w_in, w_off, w_mask, w_out, b_off, b_mask, wtA, wtOM, wtO, bOM);

    // GEMM1 (1568 blocks) + dwln (3136 blocks) fused: independent, co-resident.
    g1_dwln_kernel<<<GEMM_BLOCKS + NPIX / 4, 256, 0, stream>>>(
        xh, wtA, b_in, xpb, w_dw, b_dw, ln_g, ln_b, x1);

    // GEMM2: compacted grid, 7 col-tiles (cols 448..511 zero, never read).
    gemm2_kernel<<<GEMM2_BLOCKS, 256, 0, stream>>>(x1, wtOM, bOM, om);

    dcn_sample_kernel<<<NPIX, 256, 0, stream>>>(xpb, om, x1 /*y1: x1 dead*/);

    // GEMM3 with fused BN+SiLU epilogue (block-wide LDS transpose) -> out.
    mfma_gemm_kernel<2><<<GEMM_BLOCKS, 256, 0, stream>>>(
        x1, wtO, b_out, out, bn_g, bn_b, bn_m, bn_v);
}

// Round 19
// 106.275 us; speedup vs baseline: 1.0233x; 1.0233x over previous
//
#include <hip/hip_runtime.h>
#include <cmath>

// Problem constants
constexpr int B_ = 4, C_ = 512, H_ = 56, W_ = 56;
constexpr int HW_ = H_ * W_;          // 3136
constexpr int NPIX = B_ * HW_;        // 12544
constexpr int G_ = 16, P_ = 9;
constexpr int NMSK = G_ * P_;         // 144
constexpr int GEMM_BLOCKS = 1568;     // (12544/64) * (512/64)
constexpr int TRANS_BLOCKS = (HW_ / 32) * (C_ / 32) * B_;   // 6272
constexpr int PREP_BLOCKS = 16 * 16 * 3;                     // 768

typedef __attribute__((ext_vector_type(8))) short short8;
typedef __attribute__((ext_vector_type(4))) float f32x4;

__device__ __forceinline__ float b2f(ushort u) {
    union { unsigned int i; float f; } v; v.i = (unsigned int)u << 16; return v.f;
}
__device__ __forceinline__ ushort f2b(float f) {
    unsigned int x = __float_as_uint(f);
    unsigned int r = (x + 0x7fffu + ((x >> 16) & 1u)) >> 16;
    return (ushort)r;
}
__device__ __forceinline__ void gload16(const ushort* g, ushort* l) {
    __builtin_amdgcn_global_load_lds(
        (const __attribute__((address_space(1))) unsigned int*)g,
        (__attribute__((address_space(3))) unsigned int*)l, 16, 0, 0);
}

// LDS union: 64x64 A/B staging (16 KB) aliases MODE2 transpose buf (17.2 KB).
union GemmSMem {
    struct { ushort As[64 * 64]; ushort Bs[64 * 64]; } s;
    float eb[64 * 67];
};

// ---------------------------------------------------------------------------
// K0 (fused): role-branched pre-stage.
//   blocks [0, 6272):   NCHW->NHWC transpose, fp32 -> bf16
//   blocks [6272, 7040): weight prep ([K][N] -> bf16 [N][K]; z=2 fuses
//                        off|mask concat: cols 0..287=w_off, 288..431=w_mask,
//                        432..511=zero; + fused bias vector)
// ---------------------------------------------------------------------------
__global__ __launch_bounds__(256) void pre_kernel(
    const float* __restrict__ x, ushort* __restrict__ xh,
    const float* __restrict__ w_in, const float* __restrict__ w_off,
    const float* __restrict__ w_mask, const float* __restrict__ w_out,
    const float* __restrict__ b_off, const float* __restrict__ b_mask,
    ushort* __restrict__ wtA, ushort* __restrict__ wtOM, ushort* __restrict__ wtO,
    float* __restrict__ bOM)
{
    __shared__ float tile[32][33];
    int bid = blockIdx.x;
    int tx = threadIdx.x, ty = threadIdx.y;
    if (bid < TRANS_BLOCKS) {
        int bx = bid % 98;
        int rem = bid / 98;
        int by = rem % 16;
        int bz = rem / 16;
        int hw0 = bx * 32, c0 = by * 32;
        const float* ib = x + (size_t)bz * C_ * HW_;
        #pragma unroll
        for (int i = ty; i < 32; i += 8)
            tile[i][tx] = ib[(size_t)(c0 + i) * HW_ + hw0 + tx];
        __syncthreads();
        ushort* ob = xh + (size_t)bz * HW_ * C_;
        #pragma unroll
        for (int i = ty; i < 32; i += 8)
            ob[(size_t)(hw0 + i) * C_ + c0 + tx] = f2b(tile[tx][i]);
    } else {
        int p = bid - TRANS_BLOCKS;
        int px = p % 16;
        int py = (p / 16) % 16;
        int pz = p / 256;
        int k0 = px * 32;   // K (input row)
        int n0 = py * 32;   // N (input col / output row)
        for (int i = ty; i < 32; i += 8) {
            int k = k0 + i, n = n0 + tx;
            float v;
            if (pz == 0) v = w_in[k * 512 + n];
            else if (pz == 1) v = w_out[k * 512 + n];
            else v = (n < 288) ? w_off[k * 288 + n]
                               : (n < 432 ? w_mask[k * 144 + (n - 288)] : 0.f);
            tile[i][tx] = v;
        }
        __syncthreads();
        ushort* dst = (pz == 0) ? wtA : (pz == 1 ? wtO : wtOM);
        for (int i = ty; i < 32; i += 8)
            dst[(size_t)(n0 + i) * 512 + k0 + tx] = f2b(tile[tx][i]);
        if (pz == 2 && px == 0 && py == 0) {
            int t = ty * 32 + tx;
            for (int tt = t; tt < 512; tt += 256)
                bOM[tt] = (tt < 288) ? b_off[tt] : (tt < 432 ? b_mask[tt - 288] : 0.f);
        }
    }
}

// ---------------------------------------------------------------------------
// GEMM body.  C[M=12544 x 512] = A[M x 512]bf16 * Bt^T + bias.
// BM=BN=64, BK=64, 4 waves 2x2 (32x32/wave). 1568 blocks -> ~6/CU TLP.
// Single-buffered (dbuf = 5.4M conflicts, R8). Chunk-XOR LDS layout.
// MODE: 0 = fp32 out; 1 = bf16 out; 2 = BN+SiLU -> NCHW fp32 via block-wide
// [64][67] LDS transpose (256 B coalesced channel-plane stores).
// SKIPC7: skip col-tile 7 (cols 448..511 all-zero, unread downstream).
// ---------------------------------------------------------------------------
template <int MODE>
__device__ __forceinline__ void gemm_body(
    ushort* __restrict__ As, ushort* __restrict__ Bs, float* __restrict__ ebf,
    int wgid, const ushort* __restrict__ A, const ushort* __restrict__ Bt,
    const float* __restrict__ bias, void* __restrict__ Cout,
    const float* __restrict__ bng, const float* __restrict__ bnb,
    const float* __restrict__ bnm, const float* __restrict__ bnv)
{
    int tid = threadIdx.x;
    int lane = tid & 63, wid = tid >> 6;
    int row0 = (wgid >> 3) * 64, col0 = (wgid & 7) * 64;
    int wm = wid >> 1, wn = wid & 1;

    f32x4 acc[2][2] = {};

    int lr = lane >> 3;               // sub-row within 8-row stripe
    int sc = (lane & 7) ^ lr;         // swizzled source chunk (0..7)

    for (int k0 = 0; k0 < 512; k0 += 64) {
        if (k0) __syncthreads();
        #pragma unroll
        for (int i = 0; i < 2; i++) {
            int s = wid * 2 + i;              // 8-row stripe index (0..7)
            gload16(A + (size_t)(row0 + s * 8 + lr) * 512 + k0 + sc * 8, &As[s * 512]);
            gload16(Bt + (size_t)(col0 + s * 8 + lr) * 512 + k0 + sc * 8, &Bs[s * 512]);
        }
        __syncthreads();
        #pragma unroll
        for (int ks = 0; ks < 2; ks++) {
            short8 af[2], bf[2];
            #pragma unroll
            for (int mi = 0; mi < 2; mi++) {
                int r = wm * 32 + mi * 16 + (lane & 15);
                int c = ((lane >> 4) + ks * 4) ^ (r & 7);
                af[mi] = *(const short8*)((const char*)As + r * 128 + c * 16);
            }
            #pragma unroll
            for (int ni = 0; ni < 2; ni++) {
                int r = wn * 32 + ni * 16 + (lane & 15);
                int c = ((lane >> 4) + ks * 4) ^ (r & 7);
                bf[ni] = *(const short8*)((const char*)Bs + r * 128 + c * 16);
            }
            #pragma unroll
            for (int mi = 0; mi < 2; mi++)
                #pragma unroll
                for (int ni = 0; ni < 2; ni++)
                    acc[mi][ni] = __builtin_amdgcn_mfma_f32_16x16x32_bf16(
                        af[mi], bf[ni], acc[mi][ni], 0, 0, 0);
        }
    }

    if constexpr (MODE == 2) {
        __syncthreads();   // ebf aliases As/Bs: wait for all waves' MFMAs
        #pragma unroll
        for (int ni = 0; ni < 2; ni++) {
            int cl = wn * 32 + ni * 16 + (lane & 15);    // local chan 0..63
            int col = col0 + cl;
            float bv = bias[col];
            float inv = rsqrtf(bnv[col] + 1e-5f);
            float bsc = bng[col] * inv;
            float bsh = bnb[col] - bnm[col] * bsc;
            int rl = (lane >> 4) * 4;
            #pragma unroll
            for (int mi = 0; mi < 2; mi++)
                #pragma unroll
                for (int r = 0; r < 4; r++) {
                    float val = acc[mi][ni][r] + bv;
                    float t2 = val * bsc + bsh;
                    float s = t2 / (1.f + expf(-t2));
                    ebf[cl * 67 + wm * 32 + mi * 16 + rl + r] = s;
                }
        }
        __syncthreads();
        int bb = row0 / HW_;
        int hw0 = row0 - bb * HW_;    // 64-blocks never cross batch (3136%64==0)
        float* ob = (float*)Cout + (size_t)bb * C_ * HW_ + hw0 + lane;
        #pragma unroll
        for (int it = 0; it < 16; it++) {
            int chan = it * 4 + wid;
            ob[(size_t)(col0 + chan) * HW_] = ebf[chan * 67 + lane];
        }
    } else {
        #pragma unroll
        for (int ni = 0; ni < 2; ni++) {
            int col = col0 + wn * 32 + ni * 16 + (lane & 15);
            float bv = bias[col];
            #pragma unroll
            for (int mi = 0; mi < 2; mi++) {
                int rowb = row0 + wm * 32 + mi * 16 + (lane >> 4) * 4;
                #pragma unroll
                for (int r = 0; r < 4; r++) {
                    float val = acc[mi][ni][r] + bv;
                    if constexpr (MODE == 0)
                        ((float*)Cout)[(size_t)(rowb + r) * 512 + col] = val;
                    else
                        ((ushort*)Cout)[(size_t)(rowb + r) * 512 + col] = f2b(val);
                }
            }
        }
    }
}

template <int MODE, bool SKIPC7 = false>
__global__ __launch_bounds__(256) void mfma_gemm_kernel(
    const ushort* __restrict__ A, const ushort* __restrict__ Bt,
    const float* __restrict__ bias, void* __restrict__ Cout,
    const float* __restrict__ bng, const float* __restrict__ bnb,
    const float* __restrict__ bnm, const float* __restrict__ bnv)
{
    __shared__ GemmSMem sm;
    int bid = blockIdx.x;
    int wgid = (bid & 7) * (GEMM_BLOCKS / 8) + (bid >> 3);   // XCD chunks
    if (SKIPC7 && (wgid & 7) == 7) return;   // cols 448..511: zero, unread
    gemm_body<MODE>(sm.s.As, sm.s.Bs, sm.eb, wgid,
                    A, Bt, bias, Cout, bng, bnb, bnm, bnv);
}

// ---------------------------------------------------------------------------
// dwln body: depthwise 3x3 conv (bf16) + LayerNorm(C) + exact GELU -> bf16.
// One WAVE per pixel; XCD-swizzled block order.
// ---------------------------------------------------------------------------
__device__ __forceinline__ void dwln_body(
    int bid, const ushort* __restrict__ xh, const float* __restrict__ wdw,
    const float* __restrict__ bdw, const float* __restrict__ lng,
    const float* __restrict__ lnb, ushort* __restrict__ x1)
{
    int tid = threadIdx.x;
    int wid = tid >> 6, lane = tid & 63;
    int j = (bid & 7) * (NPIX / 32) + (bid >> 3);   // 3136 blocks, %8==0
    int n = j * 4 + wid;
    int b = n / HW_, hw = n % HW_;
    int h = hw / W_, w = hw % W_;
    int c0 = lane * 8;
    const ushort* base = xh + (size_t)b * HW_ * C_ + c0;

    uint4 nb[9];
    #pragma unroll
    for (int ky = 0; ky < 3; ky++)
        #pragma unroll
        for (int kx = 0; kx < 3; kx++) {
            int hh = h + ky - 1, ww = w + kx - 1;
            bool ok = (hh >= 0) & (hh < H_) & (ww >= 0) & (ww < W_);
            nb[ky * 3 + kx] = ok ? *(const uint4*)(base + ((size_t)hh * W_ + ww) * C_)
                                 : make_uint4(0u, 0u, 0u, 0u);
        }

    float acc[8];
    {
        float4 b0 = *(const float4*)&bdw[c0];
        float4 b1 = *(const float4*)&bdw[c0 + 4];
        acc[0] = b0.x; acc[1] = b0.y; acc[2] = b0.z; acc[3] = b0.w;
        acc[4] = b1.x; acc[5] = b1.y; acc[6] = b1.z; acc[7] = b1.w;
    }
    #pragma unroll
    for (int p = 0; p < 9; p++) {
        float4 w0 = *(const float4*)&wdw[p * C_ + c0];
        float4 w1 = *(const float4*)&wdw[p * C_ + c0 + 4];
        float wv[8] = {w0.x, w0.y, w0.z, w0.w, w1.x, w1.y, w1.z, w1.w};
        unsigned int u[4] = {nb[p].x, nb[p].y, nb[p].z, nb[p].w};
        #pragma unroll
        for (int q = 0; q < 4; q++) {
            float lo = __uint_as_float(u[q] << 16);
            float hi = __uint_as_float(u[q] & 0xffff0000u);
            acc[2 * q]     += wv[2 * q]     * lo;
            acc[2 * q + 1] += wv[2 * q + 1] * hi;
        }
    }

    float s1 = 0.f, s2 = 0.f;
    #pragma unroll
    for (int q = 0; q < 8; q++) { s1 += acc[q]; s2 += acc[q] * acc[q]; }
    #pragma unroll
    for (int o = 32; o > 0; o >>= 1) {
        s1 += __shfl_xor(s1, o);
        s2 += __shfl_xor(s2, o);
    }
    float mean = s1 * (1.f / 512.f);
    float var = s2 * (1.f / 512.f) - mean * mean;
    float inv = rsqrtf(var + 1e-6f);

    float4 g0 = *(const float4*)&lng[c0];
    float4 g1 = *(const float4*)&lng[c0 + 4];
    float4 e0 = *(const float4*)&lnb[c0];
    float4 e1 = *(const float4*)&lnb[c0 + 4];
    float gv[8] = {g0.x, g0.y, g0.z, g0.w, g1.x, g1.y, g1.z, g1.w};
    float ev[8] = {e0.x, e0.y, e0.z, e0.w, e1.x, e1.y, e1.z, e1.w};
    unsigned int outw[4];
    #pragma unroll
    for (int q = 0; q < 4; q++) {
        float t0 = (acc[2 * q]     - mean) * inv * gv[2 * q]     + ev[2 * q];
        float t1 = (acc[2 * q + 1] - mean) * inv * gv[2 * q + 1] + ev[2 * q + 1];
        float ge0 = 0.5f * t0 * (1.f + erff(t0 * 0.70710678118654752f));
        float ge1 = 0.5f * t1 * (1.f + erff(t1 * 0.70710678118654752f));
        outw[q] = (unsigned int)f2b(ge0) | ((unsigned int)f2b(ge1) << 16);
    }
    *(uint4*)&x1[(size_t)n * C_ + c0] = make_uint4(outw[0], outw[1], outw[2], outw[3]);
}

// ---------------------------------------------------------------------------
// Fused K2a: GEMM1 (MFMA-bound) CONCURRENT with dwln (latency-bound).
// ---------------------------------------------------------------------------
__global__ __launch_bounds__(256) void g1_dwln_kernel(
    const ushort* __restrict__ xh, const ushort* __restrict__ wtA,
    const float* __restrict__ b_in, ushort* __restrict__ xpb,
    const float* __restrict__ wdw, const float* __restrict__ bdw,
    const float* __restrict__ lng, const float* __restrict__ lnb,
    ushort* __restrict__ x1)
{
    __shared__ GemmSMem sm;
    int bid = blockIdx.x;
    if (bid < GEMM_BLOCKS) {
        int wgid = (bid & 7) * (GEMM_BLOCKS / 8) + (bid >> 3);
        gemm_body<1>(sm.s.As, sm.s.Bs, sm.eb, wgid,
                     xh, wtA, b_in, xpb, nullptr, nullptr, nullptr, nullptr);
    } else {
        dwln_body(bid - GEMM_BLOCKS, xh, wdw, bdw, lng, lnb, x1);
    }
}

// ---------------------------------------------------------------------------
// K4: softmax + deformable sampling (R12/R14-proven form: 1 pixel/block, 2
// channels/thread, LDS tables, 36 uint gathers register-staged). om bf16:
// [0..287]=offsets, [288..431]=logits. XCD-swizzled pixel order.
// Empirical optimum: R11 (wider gathers) null, R13 (redundant reg-prep)
// -33us, R15 (persistent 8-px pipelined) -8us. Latency hiding comes from
// 12544 small co-resident blocks (TLP).
// ---------------------------------------------------------------------------
__global__ __launch_bounds__(256) void dcn_sample_kernel(
    const ushort* __restrict__ xp, const ushort* __restrict__ om,
    ushort* __restrict__ y1)
{
    __shared__ float slog[NMSK];
    __shared__ float sw4[NMSK][4];
    __shared__ int   sa4[NMSK][4];
    int bid = blockIdx.x;
    int n = (bid & 7) * (NPIX / 8) + (bid >> 3);   // XCD-contiguous pixel bands
    int b = n / HW_, hw = n % HW_;
    int h = hw / W_, w = hw % W_;
    int tid = threadIdx.x;
    const ushort* omp = om + (size_t)n * 512;

    if (tid < NMSK) slog[tid] = b2f(omp[288 + tid]);
    __syncthreads();
    if (tid < G_) {
        float mx = -1e30f;
        #pragma unroll
        for (int p = 0; p < P_; p++) mx = fmaxf(mx, slog[tid * P_ + p]);
        float e[P_], s = 0.f;
        #pragma unroll
        for (int p = 0; p < P_; p++) { e[p] = expf(slog[tid * P_ + p] - mx); s += e[p]; }
        float invs = 1.f / s;
        #pragma unroll
        for (int p = 0; p < P_; p++) slog[tid * P_ + p] = e[p] * invs;
    }
    __syncthreads();
    if (tid < NMSK) {
        int g = tid / 9, p = tid - g * 9;
        float ox = b2f(omp[g * 18 + p * 2 + 0]);
        float oy = b2f(omp[g * 18 + p * 2 + 1]);
        float px = (float)(w + (p / 3)) + ox;   // padded coords
        float py = (float)(h + (p % 3)) + oy;
        float x0f = floorf(px), y0f = floorf(py);
        float tx = px - x0f, ty = py - y0f;
        int x0 = (int)x0f, y0 = (int)y0f;
        float m = slog[tid];
        float ww[4] = { (1.f - ty) * (1.f - tx) * m, (1.f - ty) * tx * m,
                        ty * (1.f - tx) * m,         ty * tx * m };
        #pragma unroll
        for (int i = 0; i < 4; i++) {
            int yy = y0 + (i >> 1), xx = x0 + (i & 1);
            bool valid = (yy >= 1 && yy <= H_ && xx >= 1 && xx <= W_);
            sa4[tid][i] = valid ? ((yy - 1) * W_ + (xx - 1)) * C_ : 0;
            sw4[tid][i] = valid ? ww[i] : 0.f;
        }
    }
    __syncthreads();

    const ushort* xpb = xp + (size_t)b * HW_ * C_;
    int c0 = tid * 2;
    int g = tid >> 4;

    int addr[P_][4];
    #pragma unroll
    for (int p = 0; p < P_; p++)
        #pragma unroll
        for (int i = 0; i < 4; i++)
            addr[p][i] = sa4[g * 9 + p][i] + c0;

    unsigned int v[P_][4];
    #pragma unroll
    for (int p = 0; p < P_; p++)
        #pragma unroll
        for (int i = 0; i < 4; i++)
            v[p][i] = *(const unsigned int*)(xpb + addr[p][i]);

    float ax = 0.f, ay = 0.f;
    #pragma unroll
    for (int p = 0; p < P_; p++)
        #pragma unroll
        for (int i = 0; i < 4; i++) {
            float wgt = sw4[g * 9 + p][i];
            float lo = __uint_as_float(v[p][i] << 16);
            float hi = __uint_as_float(v[p][i] & 0xffff0000u);
            ax += wgt * lo;
            ay += wgt * hi;
        }

    ushort2 o; o.x = f2b(ax); o.y = f2b(ay);
    *(ushort2*)&y1[(size_t)n * 512 + c0] = o;
}

// ---------------------------------------------------------------------------
extern "C" void kernel_launch(void* const* d_in, const int* in_sizes, int n_in,
                              void* d_out, int out_size, void* d_ws, size_t ws_size,
                              hipStream_t stream)
{
    const float* x      = (const float*)d_in[0];
    const float* w_in   = (const float*)d_in[1];
    const float* b_in   = (const float*)d_in[2];
    const float* w_dw   = (const float*)d_in[3];
    const float* b_dw   = (const float*)d_in[4];
    const float* ln_g   = (const float*)d_in[5];
    const float* ln_b   = (const float*)d_in[6];
    const float* w_off  = (const float*)d_in[7];
    const float* b_off  = (const float*)d_in[8];
    const float* w_mask = (const float*)d_in[9];
    const float* b_mask = (const float*)d_in[10];
    const float* w_out  = (const float*)d_in[11];
    const float* b_out  = (const float*)d_in[12];
    const float* bn_g   = (const float*)d_in[13];
    const float* bn_b   = (const float*)d_in[14];
    const float* bn_m   = (const float*)d_in[15];
    const float* bn_v   = (const float*)d_in[16];
    float* out = (float*)d_out;

    const size_t NC = (size_t)NPIX * C_;         // 6,422,528
    char* wsp = (char*)d_ws;
    ushort* xh  = (ushort*)wsp;  wsp += NC * 2;              // bf16 [N][C]
    ushort* x1  = (ushort*)wsp;  wsp += NC * 2;              // bf16 [N][C]; y1 alias
    ushort* xpb = (ushort*)wsp;  wsp += NC * 2;              // bf16 [N][C] (sampler in)
    ushort* om  = (ushort*)wsp;  wsp += NC * 2;              // bf16 [N][512] off|mask
    ushort* wtA = (ushort*)wsp;  wsp += 512 * 512 * 2;
    ushort* wtOM= (ushort*)wsp;  wsp += 512 * 512 * 2;
    ushort* wtO = (ushort*)wsp;  wsp += 512 * 512 * 2;
    float*  bOM = (float*)wsp;   wsp += 512 * 4;

    dim3 tb(32, 8);
    // Fused transpose + weight prep (independent, role-branched).
    pre_kernel<<<TRANS_BLOCKS + PREP_BLOCKS, tb, 0, stream>>>(
        x, xh, w_in, w_off, w_mask, w_out, b_off, b_mask, wtA, wtOM, wtO, bOM);

    // GEMM1 (1568 blocks) + dwln (3136 blocks) fused: independent, co-resident.
    g1_dwln_kernel<<<GEMM_BLOCKS + NPIX / 4, 256, 0, stream>>>(
        xh, wtA, b_in, xpb, w_dw, b_dw, ln_g, ln_b, x1);

    // GEMM2: skip col-tile 7 (cols 448..511 zero-weight, never read).
    mfma_gemm_kernel<1, true><<<GEMM_BLOCKS, 256, 0, stream>>>(
        x1, wtOM, bOM, om, nullptr, nullptr, nullptr, nullptr);

    dcn_sample_kernel<<<NPIX, 256, 0, stream>>>(xpb, om, x1 /*y1: x1 dead*/);

    // GEMM3 with fused BN+SiLU epilogue (block-wide LDS transpose) -> out.
    mfma_gemm_kernel<2><<<GEMM_BLOCKS, 256, 0, stream>>>(
        x1, wtO, b_out, out, bn_g, bn_b, bn_m, bn_v);
}